// Round 1
// baseline (168.064 us; speedup 1.0000x reference)
//
#include <hip/hip_runtime.h>
#include <hip/hip_bf16.h>

typedef unsigned short u16;
typedef __attribute__((ext_vector_type(8))) short frag_ab;  // 8 bf16 (4 VGPRs)
typedef __attribute__((ext_vector_type(4))) float f32x4;    // 4 fp32 acc

#define LDK 72  // 64 + 8 bf16 pad (16B) to break 128B-stride bank aliasing

// ---------------------------------------------------------------------------
// Shared B^T-GEMM mainloop: C[64x64 tile] = A[m0.., K] * B[n0.., K]^T
// 256 threads = 4 waves; wave w computes rows [w*16, w*16+16) x 64 cols.
// LDS-staged, BK=64 (2 mfma k-steps of 32).
// ---------------------------------------------------------------------------
__device__ __forceinline__ void gemm_bt_mainloop(
    const u16* __restrict__ A, const u16* __restrict__ B, int K,
    int m0, int n0, f32x4 acc[4], u16* As, u16* Bs)
{
    const int tid  = threadIdx.x;
    const int w    = tid >> 6;
    const int lane = tid & 63;
    const int quad = lane >> 4;
    const int l16  = lane & 15;
    const int srow = tid >> 3;        // staging row 0..31 (+32 on pass 2)
    const int scol = (tid & 7) * 8;   // staging col (8 bf16 = 16B per thread)

    for (int k0 = 0; k0 < K; k0 += 64) {
        __syncthreads();  // prior iteration's frag reads must finish
        #pragma unroll
        for (int p = 0; p < 2; ++p) {
            const int r = srow + p * 32;
            *(uint4*)(As + r * LDK + scol) =
                *(const uint4*)(A + (size_t)(m0 + r) * K + k0 + scol);
            *(uint4*)(Bs + r * LDK + scol) =
                *(const uint4*)(B + (size_t)(n0 + r) * K + k0 + scol);
        }
        __syncthreads();
        #pragma unroll
        for (int ks = 0; ks < 2; ++ks) {
            frag_ab a = *(const frag_ab*)(As + (w * 16 + l16) * LDK + ks * 32 + quad * 8);
            #pragma unroll
            for (int nt = 0; nt < 4; ++nt) {
                frag_ab b = *(const frag_ab*)(Bs + (nt * 16 + l16) * LDK + ks * 32 + quad * 8);
                acc[nt] = __builtin_amdgcn_mfma_f32_16x16x32_bf16(a, b, acc[nt], 0, 0, 0);
            }
        }
    }
}

// ---------------------------------------------------------------------------
// x[B,C,H*W] -> xs_bf16[B*s, C]  (tiled 32x32 transpose + bf16 cast)
// ---------------------------------------------------------------------------
__global__ __launch_bounds__(256) void transpose_x_kernel(
    const float* __restrict__ x, __hip_bfloat16* __restrict__ xs_bf)
{
    __shared__ float tile[32][33];
    const int b  = blockIdx.z;
    const int c0 = blockIdx.y * 32;
    const int i0 = blockIdx.x * 32;
    const int tx = threadIdx.x, ty = threadIdx.y;
    const float* xp = x + ((size_t)b * 512 + c0) * 1024 + i0;
    #pragma unroll
    for (int r = ty; r < 32; r += 8)
        tile[r][tx] = xp[(size_t)r * 1024 + tx];   // coalesced along i
    __syncthreads();
    __hip_bfloat16* op = xs_bf + ((size_t)b * 1024 + i0) * 512 + c0;
    #pragma unroll
    for (int r = ty; r < 32; r += 8)
        op[(size_t)r * 512 + tx] = __float2bfloat16(tile[tx][r]);  // coalesced along c
}

__global__ void f2bf_kernel(const float* __restrict__ in,
                            __hip_bfloat16* __restrict__ out, int n)
{
    const int idx = blockIdx.x * blockDim.x + threadIdx.x;
    if (idx < n) out[idx] = __float2bfloat16(in[idx]);
}

// ---------------------------------------------------------------------------
// qkv = xs @ Wp^T + bp, scattered to Q[bh,i,d], K[bh,j,d], Vt[bh,d,j] (bf16)
// ---------------------------------------------------------------------------
__global__ __launch_bounds__(256) void qkv_gemm_kernel(
    const u16* __restrict__ xsb, const u16* __restrict__ Wpb,
    const float* __restrict__ bp,
    __hip_bfloat16* __restrict__ Qb, __hip_bfloat16* __restrict__ Kb,
    __hip_bfloat16* __restrict__ Vtb)
{
    __shared__ u16 As[64 * LDK];
    __shared__ u16 Bs[64 * LDK];
    f32x4 acc[4];
    #pragma unroll
    for (int nt = 0; nt < 4; ++nt) { acc[nt][0]=0.f; acc[nt][1]=0.f; acc[nt][2]=0.f; acc[nt][3]=0.f; }
    const int m0 = blockIdx.x * 64, n0 = blockIdx.y * 64;
    gemm_bt_mainloop(xsb, Wpb, 512, m0, n0, acc, As, Bs);

    const int tid = threadIdx.x;
    const int w = tid >> 6, lane = tid & 63, quad = lane >> 4, l16 = lane & 15;
    #pragma unroll
    for (int nt = 0; nt < 4; ++nt) {
        const int n  = n0 + nt * 16 + l16;     // 0..1535
        const int h  = n / 192;
        const int rr = n - h * 192;            // 0..191 -> q|k|v
        const float bias = bp[n];
        #pragma unroll
        for (int r = 0; r < 4; ++r) {
            const int m = m0 + w * 16 + quad * 4 + r;  // 0..4095
            const int b = m >> 10, i = m & 1023;
            const __hip_bfloat16 hv = __float2bfloat16(acc[nt][r] + bias);
            const size_t bh = (size_t)(b * 8 + h);
            if (rr < 64)        Qb[((bh * 1024 + i) << 6) + rr] = hv;
            else if (rr < 128)  Kb[((bh * 1024 + i) << 6) + (rr - 64)] = hv;
            else                Vtb[((bh * 64 + (rr - 128)) << 10) + i] = hv;
        }
    }
}

// ---------------------------------------------------------------------------
// Flash-style attention: one block per (bh, 64-row q tile); 4 waves x 16 rows.
// S = Q K^T * 0.125 -> online softmax -> O += P V   (P via LDS layout swap)
// ---------------------------------------------------------------------------
__global__ __launch_bounds__(256) void attn_kernel(
    const __hip_bfloat16* __restrict__ Qb, const __hip_bfloat16* __restrict__ Kb,
    const __hip_bfloat16* __restrict__ Vtb, __hip_bfloat16* __restrict__ resb)
{
    __shared__ __hip_bfloat16 Ps[64 * LDK];
    const int bh = blockIdx.x;   // b*8+h, 0..31
    const int qb = blockIdx.y;   // q tile, 0..15
    const int tid = threadIdx.x;
    const int w = tid >> 6, lane = tid & 63, quad = lane >> 4, l16 = lane & 15;

    const u16* Qp = (const u16*)Qb + (size_t)bh * 1024 * 64;
    const u16* Kp = (const u16*)Kb + (size_t)bh * 1024 * 64;
    const u16* Vp = (const u16*)Vtb + (size_t)bh * 64 * 1024;

    // Q fragment (A-layout): row = qb*64 + w*16 + (lane&15), 2 k-steps
    frag_ab aq[2];
    {
        const u16* qptr = Qp + (size_t)(qb * 64 + w * 16 + l16) * 64 + quad * 8;
        aq[0] = *(const frag_ab*)(qptr);
        aq[1] = *(const frag_ab*)(qptr + 32);
    }

    float m_i[4], l_i[4];
    f32x4 o_acc[4];
    #pragma unroll
    for (int r = 0; r < 4; ++r) { m_i[r] = -1e30f; l_i[r] = 0.f; }
    #pragma unroll
    for (int d = 0; d < 4; ++d) { o_acc[d][0]=0.f; o_acc[d][1]=0.f; o_acc[d][2]=0.f; o_acc[d][3]=0.f; }

    for (int jt = 0; jt < 16; ++jt) {
        // ---- S = Q K^T (16 x 64 per wave) ----
        f32x4 s_acc[4];
        #pragma unroll
        for (int nt = 0; nt < 4; ++nt) { s_acc[nt][0]=0.f; s_acc[nt][1]=0.f; s_acc[nt][2]=0.f; s_acc[nt][3]=0.f; }
        #pragma unroll
        for (int nt = 0; nt < 4; ++nt) {
            const u16* kp = Kp + (size_t)(jt * 64 + nt * 16 + l16) * 64 + quad * 8;
            frag_ab b0 = *(const frag_ab*)(kp);
            frag_ab b1 = *(const frag_ab*)(kp + 32);
            s_acc[nt] = __builtin_amdgcn_mfma_f32_16x16x32_bf16(aq[0], b0, s_acc[nt], 0, 0, 0);
            s_acc[nt] = __builtin_amdgcn_mfma_f32_16x16x32_bf16(aq[1], b1, s_acc[nt], 0, 0, 0);
        }
        // ---- online softmax; row = quad*4+r spread across the quad's 16 lanes ----
        float p[4][4];
        #pragma unroll
        for (int r = 0; r < 4; ++r) {
            float mx = fmaxf(fmaxf(s_acc[0][r], s_acc[1][r]),
                             fmaxf(s_acc[2][r], s_acc[3][r])) * 0.125f;
            #pragma unroll
            for (int off = 1; off < 16; off <<= 1) mx = fmaxf(mx, __shfl_xor(mx, off));
            const float newm  = fmaxf(m_i[r], mx);
            const float alpha = __expf(m_i[r] - newm);
            float sum = 0.f;
            #pragma unroll
            for (int nt = 0; nt < 4; ++nt) {
                const float pv = __expf(s_acc[nt][r] * 0.125f - newm);
                p[nt][r] = pv;
                sum += pv;
            }
            #pragma unroll
            for (int off = 1; off < 16; off <<= 1) sum += __shfl_xor(sum, off);
            l_i[r] = l_i[r] * alpha + sum;
            m_i[r] = newm;
            #pragma unroll
            for (int d = 0; d < 4; ++d) o_acc[d][r] *= alpha;
        }
        // ---- P: C-layout -> A-layout via LDS ----
        __syncthreads();  // prior PV frag reads done before overwrite
        #pragma unroll
        for (int nt = 0; nt < 4; ++nt)
            #pragma unroll
            for (int r = 0; r < 4; ++r)
                Ps[(w * 16 + quad * 4 + r) * LDK + nt * 16 + l16] = __float2bfloat16(p[nt][r]);
        __syncthreads();
        // ---- O += P V  (V as B^T from Vt[d, j]) ----
        #pragma unroll
        for (int ks = 0; ks < 2; ++ks) {
            frag_ab ap = *(const frag_ab*)((const u16*)Ps + (w * 16 + l16) * LDK + ks * 32 + quad * 8);
            #pragma unroll
            for (int d = 0; d < 4; ++d) {
                frag_ab bv = *(const frag_ab*)(Vp + (size_t)(d * 16 + l16) * 1024 + jt * 64 + ks * 32 + quad * 8);
                o_acc[d] = __builtin_amdgcn_mfma_f32_16x16x32_bf16(ap, bv, o_acc[d], 0, 0, 0);
            }
        }
    }
    // ---- epilogue: res[b*1024+i, h*64+d] = O / l ----
    #pragma unroll
    for (int r = 0; r < 4; ++r) l_i[r] = 1.f / l_i[r];
    const int b = bh >> 3, h = bh & 7;
    #pragma unroll
    for (int d = 0; d < 4; ++d) {
        const int col = h * 64 + d * 16 + l16;
        #pragma unroll
        for (int r = 0; r < 4; ++r) {
            const int i = qb * 64 + w * 16 + quad * 4 + r;
            resb[((size_t)(b * 1024 + i)) * 512 + col] = __float2bfloat16(o_acc[d][r] * l_i[r]);
        }
    }
}

// ---------------------------------------------------------------------------
// out = res @ Wo^T + bo + xs, stored transposed to [B,C,H*W].
// Residual xs[b,i,c] == x[b,c,i] == x at the SAME flat index as the store.
// ---------------------------------------------------------------------------
__global__ __launch_bounds__(256) void out_gemm_kernel(
    const u16* __restrict__ resb, const u16* __restrict__ Wob,
    const float* __restrict__ bo, const float* __restrict__ x,
    float* __restrict__ out)
{
    __shared__ u16 As[64 * LDK];
    __shared__ u16 Bs[64 * LDK];
    f32x4 acc[4];
    #pragma unroll
    for (int nt = 0; nt < 4; ++nt) { acc[nt][0]=0.f; acc[nt][1]=0.f; acc[nt][2]=0.f; acc[nt][3]=0.f; }
    const int m0 = blockIdx.x * 64, n0 = blockIdx.y * 64;
    gemm_bt_mainloop(resb, Wob, 512, m0, n0, acc, As, Bs);

    const int tid = threadIdx.x;
    const int w = tid >> 6, lane = tid & 63, quad = lane >> 4, l16 = lane & 15;
    #pragma unroll
    for (int nt = 0; nt < 4; ++nt) {
        const int n = n0 + nt * 16 + l16;   // channel c, 0..511
        const float bias = bo[n];
        #pragma unroll
        for (int r = 0; r < 4; ++r) {
            const int m = m0 + w * 16 + quad * 4 + r;
            const size_t oidx = (((size_t)(m >> 10) * 512 + n) << 10) + (m & 1023);
            out[oidx] = acc[nt][r] + bias + x[oidx];
        }
    }
}

// ---------------------------------------------------------------------------
extern "C" void kernel_launch(void* const* d_in, const int* in_sizes, int n_in,
                              void* d_out, int out_size, void* d_ws, size_t ws_size,
                              hipStream_t stream)
{
    const float* x  = (const float*)d_in[0];   // [4,512,32,32]
    const float* Wp = (const float*)d_in[1];   // [1536,512]
    const float* bp = (const float*)d_in[2];   // [1536]
    const float* Wo = (const float*)d_in[3];   // [512,512]
    const float* bo = (const float*)d_in[4];   // [512]
    float* out = (float*)d_out;                // [4,512,32,32] fp32

    char* ws = (char*)d_ws;
    size_t off = 0;
    auto carve = [&](size_t bytes) -> void* {
        void* ptr = ws + off;
        off += (bytes + 255) & ~(size_t)255;
        return ptr;
    };
    __hip_bfloat16* xs_bf = (__hip_bfloat16*)carve((size_t)4096 * 512 * 2);  // xs bf16
    __hip_bfloat16* Wp_bf = (__hip_bfloat16*)carve((size_t)1536 * 512 * 2);
    __hip_bfloat16* Wo_bf = (__hip_bfloat16*)carve((size_t)512 * 512 * 2);
    __hip_bfloat16* Qb    = (__hip_bfloat16*)carve((size_t)32 * 1024 * 64 * 2);
    __hip_bfloat16* Kb    = (__hip_bfloat16*)carve((size_t)32 * 1024 * 64 * 2);
    __hip_bfloat16* Vtb   = (__hip_bfloat16*)carve((size_t)32 * 64 * 1024 * 2);
    __hip_bfloat16* resb  = (__hip_bfloat16*)carve((size_t)4096 * 512 * 2);
    // total ~22 MB of d_ws

    transpose_x_kernel<<<dim3(32, 16, 4), dim3(32, 8), 0, stream>>>(x, xs_bf);
    f2bf_kernel<<<dim3((1536 * 512 + 255) / 256), 256, 0, stream>>>(Wp, Wp_bf, 1536 * 512);
    f2bf_kernel<<<dim3((512 * 512 + 255) / 256), 256, 0, stream>>>(Wo, Wo_bf, 512 * 512);
    qkv_gemm_kernel<<<dim3(64, 24), 256, 0, stream>>>(
        (const u16*)xs_bf, (const u16*)Wp_bf, bp, Qb, Kb, Vtb);
    attn_kernel<<<dim3(32, 16), 256, 0, stream>>>(Qb, Kb, Vtb, resb);
    out_gemm_kernel<<<dim3(64, 8), 256, 0, stream>>>(
        (const u16*)resb, (const u16*)Wo_bf, bo, x, out);
}